// Round 1
// baseline (715.414 us; speedup 1.0000x reference)
//
#include <hip/hip_runtime.h>

// EMA over time axis: sta_t = sta_{t-1} + 0.6*(x_t - sta_{t-1})
// wave: [B=4096, T=6000, C=3] float32, row-major. Output same shape.
//
// Decay 0.4^L makes the recurrence effectively windowed (~16 steps to f32
// noise). Each thread owns a 128-timestep chunk of one row, warms up 16
// timesteps from sta=0 (error ~4e-7), then emits its chunk. No carries,
// no inter-thread sync. 4 timesteps = 12 floats = 3 float4 (all aligned).

constexpr int B_  = 4096;
constexpr int T_  = 6000;
constexpr int C_  = 3;
constexpr int CH  = 128;                    // timesteps per thread
constexpr int W_  = 16;                     // warm-up timesteps (0.4^16 ~ 4e-7)
constexpr int NC  = (T_ + CH - 1) / CH;     // 47 chunks per row
constexpr float STA_W = 0.6f;

__global__ __launch_bounds__(256) void ema_kernel(const float* __restrict__ x,
                                                  float* __restrict__ y) {
    int g  = blockIdx.x * blockDim.x + threadIdx.x;
    int b  = g / NC;
    int ck = g - b * NC;
    if (b >= B_) return;

    const int t0     = ck * CH;
    const int tstart = (t0 == 0) ? 0 : (t0 - W_);
    const int tend   = (t0 + CH < T_) ? (t0 + CH) : T_;

    const float4* __restrict__ xp =
        reinterpret_cast<const float4*>(x + (size_t)b * (T_ * C_) + (size_t)tstart * C_);
    float4* __restrict__ yp =
        reinterpret_cast<float4*>(y + (size_t)b * (T_ * C_) + (size_t)t0 * C_);

    float s0 = 0.f, s1 = 0.f, s2 = 0.f;
    const float w = STA_W;

    // Warm-up: (t0 - tstart) timesteps, 4 timesteps (3 float4) per iter.
    const int nwarm = (t0 - tstart) >> 2;   // 0 or 4 macro-iters
    for (int i = 0; i < nwarm; ++i) {
        float4 v0 = xp[0], v1 = xp[1], v2 = xp[2];
        xp += 3;
        // channel pattern across 12 flat floats: 0,1,2,0,1,2,...
        s0 += w * (v0.x - s0);
        s1 += w * (v0.y - s1);
        s2 += w * (v0.z - s2);
        s0 += w * (v0.w - s0);
        s1 += w * (v1.x - s1);
        s2 += w * (v1.y - s2);
        s0 += w * (v1.z - s0);
        s1 += w * (v1.w - s1);
        s2 += w * (v2.x - s2);
        s0 += w * (v2.y - s0);
        s1 += w * (v2.z - s1);
        s2 += w * (v2.w - s2);
    }

    // Main: emit outputs. (tend - t0) is 128 or 112, both divisible by 4.
    const int nmain = (tend - t0) >> 2;
    for (int i = 0; i < nmain; ++i) {
        float4 v0 = xp[0], v1 = xp[1], v2 = xp[2];
        xp += 3;
        float4 o0, o1, o2;
        s0 += w * (v0.x - s0); o0.x = s0;
        s1 += w * (v0.y - s1); o0.y = s1;
        s2 += w * (v0.z - s2); o0.z = s2;
        s0 += w * (v0.w - s0); o0.w = s0;
        s1 += w * (v1.x - s1); o1.x = s1;
        s2 += w * (v1.y - s2); o1.y = s2;
        s0 += w * (v1.z - s0); o1.z = s0;
        s1 += w * (v1.w - s1); o1.w = s1;
        s2 += w * (v2.x - s2); o2.x = s2;
        s0 += w * (v2.y - s0); o2.y = s0;
        s1 += w * (v2.z - s1); o2.z = s1;
        s2 += w * (v2.w - s2); o2.w = s2;
        yp[0] = o0; yp[1] = o1; yp[2] = o2;
        yp += 3;
    }
}

extern "C" void kernel_launch(void* const* d_in, const int* in_sizes, int n_in,
                              void* d_out, int out_size, void* d_ws, size_t ws_size,
                              hipStream_t stream) {
    const float* x = (const float*)d_in[0];
    float* y = (float*)d_out;
    const int total_threads = B_ * NC;            // 192512
    const int block = 256;
    const int grid = (total_threads + block - 1) / block;  // 752
    ema_kernel<<<grid, block, 0, stream>>>(x, y);
}

// Round 2
// 505.394 us; speedup vs baseline: 1.4156x; 1.4156x over previous
//
#include <hip/hip_runtime.h>

// EMA: sta_t = sta_{t-1} + 0.6*(x_t - sta_{t-1}), over T axis of [4096,6000,3] f32.
//
// R1 counters showed 2.07x HBM write amplification from lane-strided 16B stores
// (64B granule, no inter-instruction merging) + only 26% occupancy.
// R2 design:
//   - chunk = 48 ts (= 576B = 36 float4) per lane; 125 chunks/row (exact).
//   - wave = 64 consecutive global chunks => one contiguous 36,864B region.
//     8000 full waves, no idle lanes (region may span row boundaries; chunks don't).
//   - per lane: recurrence in registers, 16-ts tiles; outputs transposed via LDS
//     so each global store instruction writes 16 complete aligned 64B granules.
//   - warm-up (windowed, W=16, err ~0.4^16): lane computes tail-EMA of its own
//     last 16 ts, shfl_up(1) gives the neighbor's init. Row-start chunk -> 0.
//     Lane 0 of a wave loads its 192B warm-up directly (pred., ~1.6MB total).

constexpr float EW = 0.6f;
constexpr int NC_ROW = 125;   // chunks per row = 6000/48
constexpr int PITCH  = 13;    // float4 pitch per LDS slice (12 data + 1 pad)

// accumulate EMA over 3 float4 = 4 timesteps; channels cycle 0,1,2
#define ACC3(v0,v1,v2) do{ \
  a0 += EW*((v0).x-a0); a1 += EW*((v0).y-a1); a2 += EW*((v0).z-a2); \
  a0 += EW*((v0).w-a0); a1 += EW*((v1).x-a1); a2 += EW*((v1).y-a2); \
  a0 += EW*((v1).z-a0); a1 += EW*((v1).w-a1); a2 += EW*((v2).x-a2); \
  a0 += EW*((v2).y-a0); a1 += EW*((v2).z-a1); a2 += EW*((v2).w-a2); \
}while(0)

// same but writes outputs in place
#define STEP3(v0,v1,v2) do{ \
  s0 += EW*((v0).x-s0); (v0).x=s0; s1 += EW*((v0).y-s1); (v0).y=s1; s2 += EW*((v0).z-s2); (v0).z=s2; \
  s0 += EW*((v0).w-s0); (v0).w=s0; s1 += EW*((v1).x-s1); (v1).x=s1; s2 += EW*((v1).y-s2); (v1).y=s2; \
  s0 += EW*((v1).z-s0); (v1).z=s0; s1 += EW*((v1).w-s1); (v1).w=s1; s2 += EW*((v2).x-s2); (v2).x=s2; \
  s0 += EW*((v2).y-s0); (v2).y=s0; s1 += EW*((v2).z-s1); (v2).z=s1; s2 += EW*((v2).w-s2); (v2).w=s2; \
}while(0)

__global__ __launch_bounds__(256) void ema_kernel(const float* __restrict__ x,
                                                  float* __restrict__ y) {
    __shared__ float4 lds[4][64 * PITCH];          // 53,248 B -> 3 blocks/CU
    const int wave = threadIdx.x >> 6;
    const int lane = threadIdx.x & 63;
    const int w    = blockIdx.x * 4 + wave;        // wave id, 0..7999
    const int c    = w * 64 + lane;                // global chunk id, 0..511999
    const int cmod = c % NC_ROW;                   // 0 => chunk starts a row

    const float4* __restrict__ xf = (const float4*)x;
    float4*       __restrict__ yf = (float4*)y;
    const size_t base = (size_t)w * 2304 + (size_t)lane * 36;  // float4 units

    // ---- load own tail (ts 32..48 of chunk) = tile-2 data, reused later
    float4 t0,t1,t2,t3,t4,t5,t6,t7,t8,t9,t10,t11;
    {
        const float4* p = xf + base + 24;
        t0=p[0]; t1=p[1]; t2=p[2]; t3=p[3]; t4=p[4]; t5=p[5];
        t6=p[6]; t7=p[7]; t8=p[8]; t9=p[9]; t10=p[10]; t11=p[11];
    }
    float a0=0.f, a1=0.f, a2=0.f;
    ACC3(t0,t1,t2); ACC3(t3,t4,t5); ACC3(t6,t7,t8); ACC3(t9,t10,t11);

    // neighbor's warm-up init
    float i0 = __shfl_up(a0,1), i1 = __shfl_up(a1,1), i2 = __shfl_up(a2,1);
    if (lane == 0 && cmod != 0) {
        const float4* p = xf + base - 12;          // 16 ts before my chunk
        float4 u0=p[0],u1=p[1],u2=p[2],u3=p[3],u4=p[4],u5=p[5],
               u6=p[6],u7=p[7],u8=p[8],u9=p[9],u10=p[10],u11=p[11];
        a0=0.f; a1=0.f; a2=0.f;
        ACC3(u0,u1,u2); ACC3(u3,u4,u5); ACC3(u6,u7,u8); ACC3(u9,u10,u11);
        i0=a0; i1=a1; i2=a2;
    }
    if (cmod == 0) { i0=0.f; i1=0.f; i2=0.f; }     // exact at row start

    float s0=i0, s1=i1, s2=i2;
    float4* Lw = &lds[wave][0];
    const int g  = lane & 3;
    const int sb = lane >> 2;

    #pragma unroll
    for (int j = 0; j < 3; ++j) {
        float4 v0,v1,v2,v3,v4,v5,v6,v7,v8,v9,v10,v11;
        if (j == 2) {
            v0=t0;v1=t1;v2=t2;v3=t3;v4=t4;v5=t5;
            v6=t6;v7=t7;v8=t8;v9=t9;v10=t10;v11=t11;
        } else {
            const float4* p = xf + base + j*12;
            v0=p[0];v1=p[1];v2=p[2];v3=p[3];v4=p[4];v5=p[5];
            v6=p[6];v7=p[7];v8=p[8];v9=p[9];v10=p[10];v11=p[11];
        }
        STEP3(v0,v1,v2); STEP3(v3,v4,v5); STEP3(v6,v7,v8); STEP3(v9,v10,v11);

        {   // write own 192B slice to LDS
            float4* d = Lw + lane*PITCH;
            d[0]=v0; d[1]=v1; d[2]=v2;  d[3]=v3; d[4]=v4;  d[5]=v5;
            d[6]=v6; d[7]=v7; d[8]=v8;  d[9]=v9; d[10]=v10; d[11]=v11;
        }
        __syncthreads();
        // transposed store: 4-lane groups write complete aligned 64B granules
        #pragma unroll
        for (int p4 = 0; p4 < 4; ++p4) {
            const int s = p4*16 + sb;
            #pragma unroll
            for (int i = 0; i < 3; ++i) {
                float4 d = Lw[s*PITCH + i*4 + g];
                yf[(size_t)w*2304 + (size_t)s*36 + j*12 + i*4 + g] = d;
            }
        }
        __syncthreads();   // WAR: reads done before next tile's LDS writes
    }
}

extern "C" void kernel_launch(void* const* d_in, const int* in_sizes, int n_in,
                              void* d_out, int out_size, void* d_ws, size_t ws_size,
                              hipStream_t stream) {
    const float* x = (const float*)d_in[0];
    float* y = (float*)d_out;
    // 512,000 chunks / 64 = 8000 waves / 4 = 2000 blocks
    ema_kernel<<<2000, 256, 0, stream>>>(x, y);
}